// Round 1
// baseline (15682.352 us; speedup 1.0000x reference)
//
#include <hip/hip_runtime.h>
#include <math.h>

#define B64 64
#define H 1024
#define DD 8
#define ENC 96
#define HOR 336
#define TT 432
#define NSTEP 431   // L0/L1 steps t=0..430; t=431 = final L2-only
#define NB 128
#define KS0 32      // K=1024
#define KS1 64      // K=2048

typedef __attribute__((ext_vector_type(8))) short short8;
typedef __attribute__((ext_vector_type(4))) float f32x4;

__device__ __forceinline__ unsigned short f2bf(float x) {
    union { float f; unsigned u; } v; v.f = x;
    unsigned r = v.u + 0x7fffu + ((v.u >> 16) & 1u);
    return (unsigned short)(r >> 16);
}
__device__ __forceinline__ float sigm(float x) { return 1.0f / (1.0f + __expf(-x)); }

// A-fragment-major layout for activation matrices (KS = K/32):
// element (b, k) -> ((mt*KS + ks)*64 + lane)*8 + j  with
// mt=b>>4, lane=(b&15)|(((k>>3)&3)<<4), ks=k>>5, j=k&7
__device__ __forceinline__ int afrag(int b, int k, int KS) {
    return (((b >> 4) * KS + (k >> 5)) * 64 + ((b & 15) | (((k >> 3) & 3) << 4))) * 8 + (k & 7);
}

// ---------------- prep kernels ----------------

__global__ void zero_k(unsigned int* __restrict__ p, int n) {
    for (int i = blockIdx.x * 256 + threadIdx.x; i < n; i += gridDim.x * 256) p[i] = 0u;
}

// pack whh0 (4096x1024) -> Wp0 [nb:128][nt:2][ks:32][lane:64][j:8] bf16
__global__ void pack0_k(const float* __restrict__ w, unsigned short* __restrict__ dst) {
    const int total = NB * 2 * KS0 * 64 * 8;
    for (int idx = blockIdx.x * 256 + threadIdx.x; idx < total; idx += gridDim.x * 256) {
        int j = idx & 7, lane = (idx >> 3) & 63, ks = (idx >> 9) & 31, nt = (idx >> 14) & 1, nb = idx >> 15;
        int rr = nt * 16 + (lane & 15);
        int row = nb * 8 + (rr >> 2) + 1024 * (rr & 3);
        int k = ks * 32 + ((lane >> 4) << 3) + j;
        dst[idx] = f2bf(w[row * 1024 + k]);
    }
}

// pack [wih1 | whh1] (4096 x 2048) -> Wp1 [nb:128][nt:2][ks:64][lane:64][j:8]
__global__ void pack1_k(const float* __restrict__ wih, const float* __restrict__ whh,
                        unsigned short* __restrict__ dst) {
    const int total = NB * 2 * KS1 * 64 * 8;
    for (int idx = blockIdx.x * 256 + threadIdx.x; idx < total; idx += gridDim.x * 256) {
        int j = idx & 7, lane = (idx >> 3) & 63, ks = (idx >> 9) & 63, nt = (idx >> 15) & 1, nb = idx >> 16;
        int rr = nt * 16 + (lane & 15);
        int row = nb * 8 + (rr >> 2) + 1024 * (rr & 3);
        int k = ks * 32 + ((lane >> 4) << 3) + j;
        float v = (k < 1024) ? wih[row * 1024 + k] : whh[row * 1024 + (k - 1024)];
        dst[idx] = f2bf(v);
    }
}

// pack wih2 (32 x 1024) -> Wp2 [nt:2][ks:32][lane:64][j:8]
__global__ void pack2_k(const float* __restrict__ w, unsigned short* __restrict__ dst) {
    const int total = 2 * KS0 * 64 * 8;
    for (int idx = blockIdx.x * 256 + threadIdx.x; idx < total; idx += gridDim.x * 256) {
        int j = idx & 7, lane = (idx >> 3) & 63, ks = (idx >> 9) & 31, nt = (idx >> 14) & 1;
        int rr = nt * 16 + (lane & 15);
        int row = (rr >> 2) + 8 * (rr & 3);
        int k = ks * 32 + ((lane >> 4) << 3) + j;
        dst[idx] = f2bf(w[row * 1024 + k]);
    }
}

__global__ void copy_y_k(const float* __restrict__ inp, float* __restrict__ y) {
    const int total = B64 * HOR * DD; // 172032
    for (int i = blockIdx.x * 256 + threadIdx.x; i < total; i += gridDim.x * 256) {
        int b = i / (HOR * DD);
        int rem = i - b * (HOR * DD);
        y[i] = inp[b * (TT * DD) + ENC * DD + rem];
    }
}

__global__ void loss_k(const float* __restrict__ pred, const float* __restrict__ y,
                       float* __restrict__ loss) {
    __shared__ float part[256];
    int tid = threadIdx.x;
    int dd = tid & 7, cc = tid >> 3;
    float s = 0.f;
    for (int i = cc; i < B64 * HOR; i += 32) {
        float d = pred[i * 8 + dd] - y[i * 8 + dd];
        s += d * d;
    }
    part[tid] = s;
    __syncthreads();
    if (tid < 8) {
        float t = 0.f;
        for (int r = 0; r < 32; ++r) t += part[r * 8 + tid];
        loss[tid] = t / (float)(B64 * HOR);
    }
}

// ---------------- main step kernels ----------------
// kA: phase1 = L2 cell of step t-1 (replicated across blocks; block 0 writes
//     state + pred); phase2 = L0 GEMM+cell of step t.
__global__ __launch_bounds__(256) void kA(
    const unsigned short* __restrict__ Wp2, const float* __restrict__ whh2, const float* __restrict__ b2v,
    const unsigned short* __restrict__ Wp0, const float* __restrict__ wih0, const float* __restrict__ b0v,
    const float* __restrict__ inp,
    const unsigned short* __restrict__ A2,
    const unsigned short* __restrict__ A0rd, unsigned short* __restrict__ A0wr,
    unsigned short* __restrict__ A1h0,
    float* __restrict__ c0,
    const float* __restrict__ h2rd, const float* __restrict__ c2rd,
    float* __restrict__ h2wr, float* __restrict__ c2wr,
    float* __restrict__ pred, int t)
{
    __shared__ float gs[B64][33];  // +1 pad: cell reads are b-major (stride 33)
    __shared__ float xt[B64][9];
    const int tid = threadIdx.x;
    const int wave = tid >> 6;
    const int lane = tid & 63;
    const int col = lane & 15;
    const int quad = lane >> 4;
    const int nb = blockIdx.x;

    if (t > 0) {  // L2 of step t-1
        f32x4 acc0 = {0.f, 0.f, 0.f, 0.f}, acc1 = {0.f, 0.f, 0.f, 0.f};
        const short8* Ab = (const short8*)A2;
        const short8* Bb = (const short8*)Wp2;
        for (int ks = 0; ks < KS0; ++ks) {
            short8 a = Ab[(wave * KS0 + ks) * 64 + lane];
            short8 w0 = Bb[ks * 64 + lane];
            short8 w1 = Bb[(KS0 + ks) * 64 + lane];
            acc0 = __builtin_amdgcn_mfma_f32_16x16x32_bf16(a, w0, acc0, 0, 0, 0);
            acc1 = __builtin_amdgcn_mfma_f32_16x16x32_bf16(a, w1, acc1, 0, 0, 0);
        }
        #pragma unroll
        for (int r = 0; r < 4; ++r) {
            int m = wave * 16 + quad * 4 + r;   // batch
            gs[m][col] = acc0[r];               // gate-row rr = col
            gs[m][16 + col] = acc1[r];
        }
        __syncthreads();
        #pragma unroll
        for (int rep = 0; rep < 2; ++rep) {
            int it = tid + rep * 256;
            int b = it & 63, u = it >> 6;
            float g4[4];
            #pragma unroll
            for (int gi = 0; gi < 4; ++gi) {
                int row = u + 8 * gi;
                float s = gs[b][u * 4 + gi] + b2v[row];
                #pragma unroll
                for (int d = 0; d < 8; ++d) s += whh2[row * 8 + d] * h2rd[b * 8 + d];
                g4[gi] = s;
            }
            float cold = c2rd[b * 8 + u];
            float cn = sigm(g4[1]) * cold + sigm(g4[0]) * tanhf(g4[2]);
            float hn = sigm(g4[3]) * tanhf(cn);
            xt[b][u] = hn;
            if (nb == 0) {
                h2wr[b * 8 + u] = hn;
                c2wr[b * 8 + u] = cn;
                if (t >= ENC) pred[(b * HOR + (t - ENC)) * DD + u] = hn;
            }
        }
        __syncthreads();
    }

    if (t < NSTEP) {  // L0 of step t
        f32x4 acc0 = {0.f, 0.f, 0.f, 0.f}, acc1 = {0.f, 0.f, 0.f, 0.f};
        const short8* Ab = (const short8*)A0rd;
        const short8* Bb = (const short8*)Wp0 + nb * (2 * KS0 * 64);
        for (int ks = 0; ks < KS0; ++ks) {
            short8 a = Ab[(wave * KS0 + ks) * 64 + lane];
            short8 w0 = Bb[ks * 64 + lane];
            short8 w1 = Bb[(KS0 + ks) * 64 + lane];
            acc0 = __builtin_amdgcn_mfma_f32_16x16x32_bf16(a, w0, acc0, 0, 0, 0);
            acc1 = __builtin_amdgcn_mfma_f32_16x16x32_bf16(a, w1, acc1, 0, 0, 0);
        }
        #pragma unroll
        for (int r = 0; r < 4; ++r) {
            int m = wave * 16 + quad * 4 + r;
            gs[m][col] = acc0[r];
            gs[m][16 + col] = acc1[r];
        }
        __syncthreads();
        #pragma unroll
        for (int rep = 0; rep < 2; ++rep) {
            int it = tid + rep * 256;
            int b = it & 63, u = it >> 6;
            int j = nb * 8 + u;
            float xv[8];
            #pragma unroll
            for (int d = 0; d < 8; ++d)
                xv[d] = (t < ENC) ? inp[(b * TT + t) * DD + d] : xt[b][d];
            float g4[4];
            #pragma unroll
            for (int gi = 0; gi < 4; ++gi) {
                int row = j + 1024 * gi;
                float s = gs[b][u * 4 + gi] + b0v[row];
                #pragma unroll
                for (int d = 0; d < 8; ++d) s += wih0[row * 8 + d] * xv[d];
                g4[gi] = s;
            }
            float cold = c0[b * H + j];
            float cn = sigm(g4[1]) * cold + sigm(g4[0]) * tanhf(g4[2]);
            float hn = sigm(g4[3]) * tanhf(cn);
            c0[b * H + j] = cn;
            unsigned short hb = f2bf(hn);
            A0wr[afrag(b, j, KS0)] = hb;
            A1h0[afrag(b, j, KS1)] = hb;
        }
    }
}

// kB: L1 GEMM+cell of step t. A1 = [h0'(t) | h1(t-1)], K=2048.
__global__ __launch_bounds__(256) void kB(
    const unsigned short* __restrict__ Wp1, const float* __restrict__ b1v,
    const unsigned short* __restrict__ A1rd,
    unsigned short* __restrict__ A1wr, unsigned short* __restrict__ A2,
    float* __restrict__ c1)
{
    __shared__ float gs[B64][33];
    const int tid = threadIdx.x;
    const int wave = tid >> 6;
    const int lane = tid & 63;
    const int col = lane & 15;
    const int quad = lane >> 4;
    const int nb = blockIdx.x;

    f32x4 acc0 = {0.f, 0.f, 0.f, 0.f}, acc1 = {0.f, 0.f, 0.f, 0.f};
    const short8* Ab = (const short8*)A1rd;
    const short8* Bb = (const short8*)Wp1 + nb * (2 * KS1 * 64);
    for (int ks = 0; ks < KS1; ++ks) {
        short8 a = Ab[(wave * KS1 + ks) * 64 + lane];
        short8 w0 = Bb[ks * 64 + lane];
        short8 w1 = Bb[(KS1 + ks) * 64 + lane];
        acc0 = __builtin_amdgcn_mfma_f32_16x16x32_bf16(a, w0, acc0, 0, 0, 0);
        acc1 = __builtin_amdgcn_mfma_f32_16x16x32_bf16(a, w1, acc1, 0, 0, 0);
    }
    #pragma unroll
    for (int r = 0; r < 4; ++r) {
        int m = wave * 16 + quad * 4 + r;
        gs[m][col] = acc0[r];
        gs[m][16 + col] = acc1[r];
    }
    __syncthreads();
    #pragma unroll
    for (int rep = 0; rep < 2; ++rep) {
        int it = tid + rep * 256;
        int b = it & 63, u = it >> 6;
        int j = nb * 8 + u;
        float g4[4];
        #pragma unroll
        for (int gi = 0; gi < 4; ++gi)
            g4[gi] = gs[b][u * 4 + gi] + b1v[j + 1024 * gi];
        float cold = c1[b * H + j];
        float cn = sigm(g4[1]) * cold + sigm(g4[0]) * tanhf(g4[2]);
        float hn = sigm(g4[3]) * tanhf(cn);
        c1[b * H + j] = cn;
        unsigned short hb = f2bf(hn);
        A1wr[afrag(b, H + j, KS1)] = hb;
        A2[afrag(b, j, KS0)] = hb;
    }
}

// ---------------- host ----------------

extern "C" void kernel_launch(void* const* d_in, const int* in_sizes, int n_in,
                              void* d_out, int out_size, void* d_ws, size_t ws_size,
                              hipStream_t stream)
{
    const float* inp  = (const float*)d_in[0];
    const float* wih0 = (const float*)d_in[1];
    const float* whh0 = (const float*)d_in[2];
    const float* b0v  = (const float*)d_in[3];
    const float* wih1 = (const float*)d_in[4];
    const float* whh1 = (const float*)d_in[5];
    const float* b1v  = (const float*)d_in[6];
    const float* wih2 = (const float*)d_in[7];
    const float* whh2 = (const float*)d_in[8];
    const float* b2v  = (const float*)d_in[9];
    float* out = (float*)d_out;   // pred[172032] | y[172032] | loss[8]

    char* base = (char*)d_ws;
    size_t off = 0;
    auto carve = [&](size_t bytes) -> void* {
        void* p = base + off;
        off += (bytes + 255) & ~((size_t)255);
        return p;
    };
    unsigned short* Wp0 = (unsigned short*)carve((size_t)NB * 2 * KS0 * 64 * 8 * 2);
    unsigned short* Wp1 = (unsigned short*)carve((size_t)NB * 2 * KS1 * 64 * 8 * 2);
    unsigned short* Wp2 = (unsigned short*)carve((size_t)2 * KS0 * 64 * 8 * 2);
    size_t state_off = off;
    float* c0 = (float*)carve(B64 * H * 4);
    float* c1 = (float*)carve(B64 * H * 4);
    unsigned short* A0a = (unsigned short*)carve(B64 * H * 2);
    unsigned short* A0b = (unsigned short*)carve(B64 * H * 2);
    unsigned short* A1a = (unsigned short*)carve(B64 * 2 * H * 2);
    unsigned short* A1b = (unsigned short*)carve(B64 * 2 * H * 2);
    unsigned short* A2  = (unsigned short*)carve(B64 * H * 2);
    float* h2a = (float*)carve(B64 * DD * 4);
    float* h2b_ = (float*)carve(B64 * DD * 4);
    float* c2a = (float*)carve(B64 * DD * 4);
    float* c2b_ = (float*)carve(B64 * DD * 4);
    size_t state_bytes = off - state_off;
    if (off > ws_size) return;  // workspace too small: fail loudly

    unsigned short* A0p[2] = {A0a, A0b};
    unsigned short* A1p[2] = {A1a, A1b};
    float* h2p[2] = {h2a, h2b_};
    float* c2p[2] = {c2a, c2b_};

    zero_k<<<512, 256, 0, stream>>>((unsigned int*)(base + state_off), (int)(state_bytes / 4));
    pack0_k<<<2048, 256, 0, stream>>>(whh0, Wp0);
    pack1_k<<<4096, 256, 0, stream>>>(wih1, whh1, Wp1);
    pack2_k<<<32, 256, 0, stream>>>(wih2, Wp2);
    copy_y_k<<<672, 256, 0, stream>>>(inp, out + 172032);

    for (int t = 0; t <= NSTEP; ++t) {
        int p = t & 1;
        kA<<<NB, 256, 0, stream>>>(Wp2, whh2, b2v, Wp0, wih0, b0v, inp,
                                   A2, A0p[p], A0p[1 - p], A1p[p], c0,
                                   h2p[(t + 1) & 1], c2p[(t + 1) & 1], h2p[p], c2p[p],
                                   out, t);
        if (t < NSTEP)
            kB<<<NB, 256, 0, stream>>>(Wp1, b1v, A1p[p], A1p[1 - p], A2, c1);
    }
    loss_k<<<1, 256, 0, stream>>>(out, out + 172032, out + 344064);
}